// Round 1
// baseline (433.263 us; speedup 1.0000x reference)
//
#include <hip/hip_runtime.h>
#include <cstddef>

#define LN_EPS 1e-5f

__device__ inline float4 ld4(const float* p) { return *reinterpret_cast<const float4*>(p); }
__device__ inline void st4(float* p, float4 v) { *reinterpret_cast<float4*>(p) = v; }

// ---------------- K-split GEMM: part[kc][row][c] = sum_{k in chunk} A[row][k] * W[k][c]
// grid (64, 4), block 256. M=1024 fixed, Nc=256 fixed.
__global__ __launch_bounds__(256) void gemmk(const float* __restrict__ A,
                                             const float* __restrict__ W,
                                             float* __restrict__ part,
                                             int K, int KC) {
  const int row0 = blockIdx.x * 16;
  const int kcs = blockIdx.y * KC;
  const int c = threadIdx.x;
  __shared__ float4 At4[16 * 9];  // 16 rows x 36 floats (32 used, padded)
  float* At = reinterpret_cast<float*>(At4);
  float acc[16];
#pragma unroll
  for (int r = 0; r < 16; ++r) acc[r] = 0.f;
  const int sr = threadIdx.x >> 4;
  const int sc = (threadIdx.x & 15) * 2;
  for (int k0 = kcs; k0 < kcs + KC; k0 += 32) {
    const float* ap = A + (size_t)(row0 + sr) * K + k0 + sc;
    float2 av = *reinterpret_cast<const float2*>(ap);
    At[sr * 36 + sc] = av.x;
    At[sr * 36 + sc + 1] = av.y;
    __syncthreads();
#pragma unroll
    for (int kk4 = 0; kk4 < 8; ++kk4) {
      const float* wp = W + (size_t)(k0 + kk4 * 4) * 256 + c;
      float w0 = wp[0], w1 = wp[256], w2 = wp[512], w3 = wp[768];
#pragma unroll
      for (int r = 0; r < 16; ++r) {
        float4 a = *reinterpret_cast<const float4*>(&At[r * 36 + kk4 * 4]);
        acc[r] = fmaf(a.x, w0, acc[r]);
        acc[r] = fmaf(a.y, w1, acc[r]);
        acc[r] = fmaf(a.z, w2, acc[r]);
        acc[r] = fmaf(a.w, w3, acc[r]);
      }
    }
    __syncthreads();
  }
  float* pp = part + ((size_t)blockIdx.y * 1024 + row0) * 256 + c;
#pragma unroll
  for (int r = 0; r < 16; ++r) pp[(size_t)r * 256] = acc[r];
}

// ---------------- transposed-A batched GEMM (upd): part[kc][b*256+n][c] = sum_e inc[b][e][n]*nt[b][e][c]
// grid (16, 4, 4), block 256
__global__ __launch_bounds__(256) void gemmtk(const float* __restrict__ incm,
                                              const float* __restrict__ nt,
                                              float* __restrict__ part) {
  const int n0 = blockIdx.x * 16;
  const int b = blockIdx.y;
  const int kcs = blockIdx.z * 64;
  const int c = threadIdx.x;
  const float* Ab = incm + (size_t)b * 65536;
  const float* Bb = nt + (size_t)b * 65536;
  __shared__ float4 At4[16 * 9];
  float* At = reinterpret_cast<float*>(At4);
  float acc[16];
#pragma unroll
  for (int r = 0; r < 16; ++r) acc[r] = 0.f;
  const int sr = threadIdx.x & 15;
  const int se = (threadIdx.x >> 4) * 2;
  for (int k0 = kcs; k0 < kcs + 64; k0 += 32) {
    At[sr * 36 + se] = Ab[(size_t)(k0 + se) * 256 + n0 + sr];
    At[sr * 36 + se + 1] = Ab[(size_t)(k0 + se + 1) * 256 + n0 + sr];
    __syncthreads();
#pragma unroll
    for (int kk4 = 0; kk4 < 8; ++kk4) {
      const float* wp = Bb + (size_t)(k0 + kk4 * 4) * 256 + c;
      float w0 = wp[0], w1 = wp[256], w2 = wp[512], w3 = wp[768];
#pragma unroll
      for (int r = 0; r < 16; ++r) {
        float4 a = *reinterpret_cast<const float4*>(&At[r * 36 + kk4 * 4]);
        acc[r] = fmaf(a.x, w0, acc[r]);
        acc[r] = fmaf(a.y, w1, acc[r]);
        acc[r] = fmaf(a.z, w2, acc[r]);
        acc[r] = fmaf(a.w, w3, acc[r]);
      }
    }
    __syncthreads();
  }
  float* pp = part + ((size_t)blockIdx.z * 1024 + b * 256 + n0) * 256 + c;
#pragma unroll
  for (int r = 0; r < 16; ++r) pp[(size_t)r * 256] = acc[r];
}

// ---------------- partial reduce + bias/rowterm/relu epilogue. grid 1024, block 256.
__global__ __launch_bounds__(256) void gred(const float* __restrict__ part,
                                            const float* __restrict__ bias,
                                            const float* __restrict__ rowterm,
                                            float* __restrict__ out, int relu) {
  const int idx = blockIdx.x * 256 + threadIdx.x;
  const int c = idx & 255;
  const int brow = idx >> 16;
  float s = part[idx] + part[idx + 262144] + part[idx + 524288] + part[idx + 786432];
  if (bias) s += bias[c];
  if (rowterm) s += rowterm[(brow << 8) + c];
  if (relu) s = fmaxf(s, 0.f);
  out[idx] = s;
}

// ---------------- adjacency stage 1: partial d-sums of relu(xp[n]+xp[e]+bi + inc*wi)*ws
// grid (4 n-tiles, 4 e-tiles, 16 = b*4+dchunk), block 256 (4x4 micro per thread over 64x64 tile)
__global__ __launch_bounds__(256) void adj1(const float* __restrict__ xp,
                                            const float* __restrict__ incold,
                                            const float* __restrict__ wi,
                                            const float* __restrict__ bi,
                                            const float* __restrict__ ws,
                                            float* __restrict__ part) {
  const int n0 = blockIdx.x * 64;
  const int e0 = blockIdx.y * 64;
  const int bz = blockIdx.z;  // b*4 + dc
  const int b = bz >> 2;
  const int d0 = (bz & 3) * 64;
  __shared__ float4 tn4[64 * 17];
  __shared__ float4 te4[64 * 17];
  __shared__ float4 wiv4[16];
  __shared__ float4 wsv4[16];
  float* tn = reinterpret_cast<float*>(tn4);
  float* te = reinterpret_cast<float*>(te4);
  float* wiv = reinterpret_cast<float*>(wiv4);
  float* wsv = reinterpret_cast<float*>(wsv4);
  const int tid = threadIdx.x;
  const int q = tid & 15;
  const int rb = tid >> 4;
  const float* xb = xp + (size_t)b * 65536;
#pragma unroll
  for (int s = 0; s < 4; ++s) {
    int rl = rb + 16 * s;
    float4 v = ld4(&xb[(size_t)(n0 + rl) * 256 + d0 + q * 4]);
    st4(&tn[rl * 68 + q * 4], v);
    float4 e = ld4(&xb[(size_t)(e0 + rl) * 256 + d0 + q * 4]);
    float4 bq = ld4(&bi[d0 + q * 4]);
    e.x += bq.x; e.y += bq.y; e.z += bq.z; e.w += bq.w;
    st4(&te[rl * 68 + q * 4], e);
  }
  if (tid < 16) {
    st4(&wiv[tid * 4], ld4(&wi[d0 + tid * 4]));
  } else if (tid < 32) {
    int t2 = tid - 16;
    st4(&wsv[t2 * 4], ld4(&ws[d0 + t2 * 4]));
  }
  const int tx = tid & 15, ty = tid >> 4;
  float incv[4][4], acc[4][4];
#pragma unroll
  for (int j = 0; j < 4; ++j) {
    const float* ib = incold + ((size_t)b * 256 + e0 + ty + 16 * j) * 256 + n0 + tx;
#pragma unroll
    for (int i = 0; i < 4; ++i) { incv[j][i] = ib[16 * i]; acc[j][i] = 0.f; }
  }
  __syncthreads();
#pragma unroll 2
  for (int dl = 0; dl < 64; dl += 4) {
    float4 wiq = ld4(&wiv[dl]);
    float4 wsq = ld4(&wsv[dl]);
    float4 xn[4], xe[4];
#pragma unroll
    for (int i = 0; i < 4; ++i) xn[i] = ld4(&tn[(tx + 16 * i) * 68 + dl]);
#pragma unroll
    for (int j = 0; j < 4; ++j) xe[j] = ld4(&te[(ty + 16 * j) * 68 + dl]);
#pragma unroll
    for (int j = 0; j < 4; ++j)
#pragma unroll
      for (int i = 0; i < 4; ++i) {
        float u;
        u = fmaf(incv[j][i], wiq.x, xn[i].x + xe[j].x); u = fmaxf(u, 0.f); acc[j][i] = fmaf(u, wsq.x, acc[j][i]);
        u = fmaf(incv[j][i], wiq.y, xn[i].y + xe[j].y); u = fmaxf(u, 0.f); acc[j][i] = fmaf(u, wsq.y, acc[j][i]);
        u = fmaf(incv[j][i], wiq.z, xn[i].z + xe[j].z); u = fmaxf(u, 0.f); acc[j][i] = fmaf(u, wsq.z, acc[j][i]);
        u = fmaf(incv[j][i], wiq.w, xn[i].w + xe[j].w); u = fmaxf(u, 0.f); acc[j][i] = fmaf(u, wsq.w, acc[j][i]);
      }
  }
#pragma unroll
  for (int j = 0; j < 4; ++j) {
    float* pp = part + ((size_t)bz * 256 + e0 + ty + 16 * j) * 256 + n0 + tx;
#pragma unroll
    for (int i = 0; i < 4; ++i) pp[16 * i] = acc[j][i];
  }
}

// ---------------- adjacency stage 2: sum 4 d-chunk partials + sigmoid. grid 1024, block 256.
__global__ __launch_bounds__(256) void adj2(const float* __restrict__ part,
                                            const float* __restrict__ bs,
                                            float* __restrict__ pred) {
  const int o = blockIdx.x * 256 + threadIdx.x;
  const int b = o >> 16;
  const int rem = o & 65535;
  const float* p = part + ((size_t)b << 18) + rem;
  float s = p[0] + p[65536] + p[131072] + p[196608] + bs[0];
  pred[o] = 1.f / (1.f + __expf(-s));
}

__device__ inline void wred2(float& s, float& q) {
#pragma unroll
  for (int off = 32; off; off >>= 1) {
    s += __shfl_xor(s, off);
    q += __shfl_xor(q, off);
  }
}

// ---------------- reduce upd partials + LayerNorm(concat(x_in, nt, upd)) -> h. grid 256, block 256 (wave/row)
__global__ __launch_bounds__(256) void gredln768(const float* __restrict__ part,
                                                 const float* __restrict__ x_in,
                                                 const float* __restrict__ nt,
                                                 const float* __restrict__ g,
                                                 const float* __restrict__ be,
                                                 float* __restrict__ h) {
  const int row = blockIdx.x * 4 + (threadIdx.x >> 6);
  const int lane = threadIdx.x & 63;
  const int c4 = lane * 4;
  const size_t ro = (size_t)row * 256 + c4;
  float4 u = ld4(&part[ro]);
  float4 u1 = ld4(&part[ro + 262144]);
  float4 u2 = ld4(&part[ro + 524288]);
  float4 u3 = ld4(&part[ro + 786432]);
  u.x += u1.x + u2.x + u3.x;
  u.y += u1.y + u2.y + u3.y;
  u.z += u1.z + u2.z + u3.z;
  u.w += u1.w + u2.w + u3.w;
  float4 xi = ld4(&x_in[ro]);
  float4 nv = ld4(&nt[ro]);
  float s = xi.x + xi.y + xi.z + xi.w + nv.x + nv.y + nv.z + nv.w + u.x + u.y + u.z + u.w;
  float sq = xi.x * xi.x + xi.y * xi.y + xi.z * xi.z + xi.w * xi.w
           + nv.x * nv.x + nv.y * nv.y + nv.z * nv.z + nv.w * nv.w
           + u.x * u.x + u.y * u.y + u.z * u.z + u.w * u.w;
  wred2(s, sq);
  float mu = s * (1.f / 768.f);
  float rs = rsqrtf(sq * (1.f / 768.f) - mu * mu + LN_EPS);
  float* hr = h + (size_t)row * 768;
  {
    float4 g4 = ld4(&g[c4]), b4 = ld4(&be[c4]), o;
    o.x = (xi.x - mu) * rs * g4.x + b4.x;
    o.y = (xi.y - mu) * rs * g4.y + b4.y;
    o.z = (xi.z - mu) * rs * g4.z + b4.z;
    o.w = (xi.w - mu) * rs * g4.w + b4.w;
    st4(&hr[c4], o);
  }
  {
    float4 g4 = ld4(&g[256 + c4]), b4 = ld4(&be[256 + c4]), o;
    o.x = (nv.x - mu) * rs * g4.x + b4.x;
    o.y = (nv.y - mu) * rs * g4.y + b4.y;
    o.z = (nv.z - mu) * rs * g4.z + b4.z;
    o.w = (nv.w - mu) * rs * g4.w + b4.w;
    st4(&hr[256 + c4], o);
  }
  {
    float4 g4 = ld4(&g[512 + c4]), b4 = ld4(&be[512 + c4]), o;
    o.x = (u.x - mu) * rs * g4.x + b4.x;
    o.y = (u.y - mu) * rs * g4.y + b4.y;
    o.z = (u.z - mu) * rs * g4.z + b4.z;
    o.w = (u.w - mu) * rs * g4.w + b4.w;
    st4(&hr[512 + c4], o);
  }
}

// ---------------- reduce z partials + mt2 + residual + LayerNorm -> dst. grid 256, block 256 (wave/row)
__global__ __launch_bounds__(256) void gredln256(const float* __restrict__ part,
                                                 const float* __restrict__ nt,
                                                 const float* __restrict__ mt2,
                                                 const float* __restrict__ g,
                                                 const float* __restrict__ be,
                                                 float* __restrict__ dst) {
  const int row = blockIdx.x * 4 + (threadIdx.x >> 6);
  const int lane = threadIdx.x & 63;
  const int c4 = lane * 4;
  const int b = row >> 8;
  const size_t ro = (size_t)row * 256 + c4;
  float4 p0 = ld4(&part[ro]);
  float4 p1 = ld4(&part[ro + 262144]);
  float4 p2 = ld4(&part[ro + 524288]);
  float4 p3 = ld4(&part[ro + 786432]);
  float4 m4 = ld4(&mt2[(b << 8) + c4]);
  float4 nv = ld4(&nt[ro]);
  float4 x;
  x.x = nv.x + p0.x + p1.x + p2.x + p3.x + m4.x;
  x.y = nv.y + p0.y + p1.y + p2.y + p3.y + m4.y;
  x.z = nv.z + p0.z + p1.z + p2.z + p3.z + m4.z;
  x.w = nv.w + p0.w + p1.w + p2.w + p3.w + m4.w;
  float s = x.x + x.y + x.z + x.w;
  float sq = x.x * x.x + x.y * x.y + x.z * x.z + x.w * x.w;
  wred2(s, sq);
  float mu = s * (1.f / 256.f);
  float rs = rsqrtf(sq * (1.f / 256.f) - mu * mu + LN_EPS);
  float4 g4 = ld4(&g[c4]), b4 = ld4(&be[c4]), o;
  o.x = (x.x - mu) * rs * g4.x + b4.x;
  o.y = (x.y - mu) * rs * g4.y + b4.y;
  o.z = (x.z - mu) * rs * g4.z + b4.z;
  o.w = (x.w - mu) * rs * g4.w + b4.w;
  st4(&dst[ro], o);
}

// ---------------- column mean over n + linear term: mt[b][c] = bias[c] + sum_k mean_n(X)[k] * Wl[k][c]
// grid (4), block Kd (768 or 256)
__global__ void meanterm(const float* __restrict__ X, const float* __restrict__ Wl,
                         const float* __restrict__ bias, float* __restrict__ mt,
                         int Kd) {
  __shared__ float ms[768];
  __shared__ float red[768];
  const int b = blockIdx.x, t = threadIdx.x;
  float s = 0.f;
  const float* xb = X + (size_t)b * 256 * Kd + t;
#pragma unroll 8
  for (int n = 0; n < 256; ++n) s += xb[(size_t)n * Kd];
  ms[t] = s * (1.f / 256.f);
  __syncthreads();
  const int c = t & 255, sl = t >> 8;
  float a = 0.f;
  const float* wb = Wl + (size_t)sl * 65536 + c;
  const float* msb = ms + sl * 256;
#pragma unroll 8
  for (int kk = 0; kk < 256; ++kk) a = fmaf(msb[kk], wb[(size_t)kk * 256], a);
  red[t] = a;
  __syncthreads();
  if (t < 256) {
    float r = bias[t] + red[t];
    for (int s2 = 1; s2 < Kd / 256; ++s2) r += red[s2 * 256 + t];
    mt[(b << 8) + t] = r;
  }
}

extern "C" void kernel_launch(void* const* d_in, const int* in_sizes, int n_in,
                              void* d_out, int out_size, void* d_ws, size_t ws_size,
                              hipStream_t stream) {
  (void)in_sizes; (void)n_in; (void)out_size; (void)ws_size;
  const float* inputs = (const float*)d_in[0];
  const float* v_t    = (const float*)d_in[1];
  const float* i_t    = (const float*)d_in[2];
  const float* Wp     = (const float*)d_in[3];
  const float* bp     = (const float*)d_in[4];
  const float* Wx     = (const float*)d_in[5];
  const float* bx     = (const float*)d_in[6];
  const float* wi     = (const float*)d_in[7];
  const float* bi     = (const float*)d_in[8];
  const float* ws     = (const float*)d_in[9];
  const float* bs     = (const float*)d_in[10];
  const float* g_pre  = (const float*)d_in[11];
  const float* be_pre = (const float*)d_in[12];
  const float* g_n    = (const float*)d_in[13];
  const float* be_n   = (const float*)d_in[14];
  const float* W1g    = (const float*)d_in[15];
  const float* W1l    = (const float*)d_in[16];
  const float* b1     = (const float*)d_in[17];
  const float* W2g    = (const float*)d_in[18];
  const float* W2l    = (const float*)d_in[19];
  const float* b2     = (const float*)d_in[20];
  float* out = (float*)d_out;
  float* wsf = (float*)d_ws;
  float* x_in = wsf;                 // 262144
  float* ntA  = wsf + 262144;        // 262144
  float* ntB  = wsf + 524288;        // 262144
  float* xp   = wsf + 786432;        // 262144
  float* h    = wsf + 1048576;       // 786432
  float* h1   = wsf + 1835008;       // 262144
  float* part = wsf + 2097152;       // 1048576
  float* mt1  = wsf + 3145728;       // 1024
  float* mt2  = wsf + 3146752;       // 1024

  hipMemcpyAsync(ntA, v_t, 262144 * sizeof(float), hipMemcpyDeviceToDevice, stream);

  // x_in = inputs @ Wp + bp
  gemmk<<<dim3(64, 4), 256, 0, stream>>>(inputs, Wp, part, 128, 32);
  gred<<<1024, 256, 0, stream>>>(part, bp, nullptr, x_in, 0);

  float* ntCur = ntA;
  float* ntNxt = ntB;
  for (int t = 0; t < 3; ++t) {
    const float* incold = (t == 0) ? i_t : (out + (size_t)(t - 1) * 262144);
    float* pred = out + (size_t)t * 262144;
    // xp = ntCur @ Wx + bx
    gemmk<<<dim3(64, 4), 256, 0, stream>>>(ntCur, Wx, part, 256, 64);
    gred<<<1024, 256, 0, stream>>>(part, bx, nullptr, xp, 0);
    // inc = sigmoid(sum_d relu(...) * ws + bs)
    adj1<<<dim3(4, 4, 16), 256, 0, stream>>>(xp, incold, wi, bi, ws, part);
    adj2<<<1024, 256, 0, stream>>>(part, bs, pred);
    // upd partials, then LN(concat) -> h
    gemmtk<<<dim3(16, 4, 4), 256, 0, stream>>>(pred, ntCur, part);
    gredln768<<<256, 256, 0, stream>>>(part, x_in, ntCur, g_pre, be_pre, h);
    // mt1 = b1 + mean(h) @ W1l ; h1 = relu(h @ W1g + mt1)
    meanterm<<<4, 768, 0, stream>>>(h, W1l, b1, mt1, 768);
    gemmk<<<dim3(64, 4), 256, 0, stream>>>(h, W1g, part, 768, 192);
    gred<<<1024, 256, 0, stream>>>(part, nullptr, mt1, h1, 1);
    // mt2 = b2 + mean(h1) @ W2l ; nt = LN(nt + h1 @ W2g + mt2)
    meanterm<<<4, 256, 0, stream>>>(h1, W2l, b2, mt2, 256);
    gemmk<<<dim3(64, 4), 256, 0, stream>>>(h1, W2g, part, 256, 64);
    float* dst = (t == 2) ? (out + 786432) : ntNxt;
    gredln256<<<256, 256, 0, stream>>>(part, ntCur, mt2, g_n, be_n, dst);
    float* tmp = ntCur; ntCur = ntNxt; ntNxt = tmp;
  }
  // final inc output = preds[2]
  hipMemcpyAsync(out + 1048576, out + 524288, 262144 * sizeof(float),
                 hipMemcpyDeviceToDevice, stream);
}